// Round 1
// baseline (210.160 us; speedup 1.0000x reference)
//
#include <hip/hip_runtime.h>
#include <stdint.h>

// ---------------------------------------------------------------------------
// MoEBiEncoder: top-1 MoE (C=16 experts), per-row 768 -> relu(384) -> 768,
// gate-scale, l2norm, +residual, l2norm.  B=16384, D=768, H=384.
//
// Pipeline: gate/argmax -> prefix-scan -> bucket rows by expert ->
//           convert+transpose+swizzle weights to bf16 -> grouped MFMA GEMM
//           with fused epilogue.
// ---------------------------------------------------------------------------

#define B_ROWS 16384
#define C_EXP  16
#define D_DIM  768
#define H_DIM  384

typedef __bf16 bf16_t;
typedef __bf16 bf16x8 __attribute__((ext_vector_type(8)));
typedef __bf16 bf16x4 __attribute__((ext_vector_type(4)));
typedef float  f32x4  __attribute__((ext_vector_type(4)));

// ---- workspace layout (bytes) ----
static constexpr size_t WS_CNT  = 0;                       // 16 int
static constexpr size_t WS_CUR  = 64;                      // 16 int
static constexpr size_t WS_OFF  = 128;                     // 17 int
static constexpr size_t WS_TOFF = 256;                     // 17 int
static constexpr size_t WS_EXP  = 512;                     // B int
static constexpr size_t WS_GATE = WS_EXP  + (size_t)B_ROWS * 4;
static constexpr size_t WS_ROW  = WS_GATE + (size_t)B_ROWS * 4;
static constexpr size_t WS_W1   = WS_ROW  + (size_t)B_ROWS * 4;   // 197120
static constexpr size_t W_BYTES = (size_t)C_EXP * D_DIM * H_DIM * 2;  // 9437184
static constexpr size_t WS_W4   = WS_W1 + W_BYTES;
static constexpr size_t WS_END  = WS_W4 + W_BYTES;         // ~18.2 MB

// w1s chunk: [kc 0..11][n 0..383][k' 0..63] bf16, 49152 B/chunk, XOR-swizzled
// w4s chunk: [kc 0..5 ][n 0..767][k' 0..63] bf16, 98304 B/chunk, XOR-swizzled
// swizzle (both LDS image and pre-baked global layout):
//   byte(n,k') = n*128 + (((k'>>3)*16) ^ ((n&7)<<4)) + (k'&7)*2

__device__ __forceinline__ void lds_load16(const void* g, void* l) {
    // CK-proven pattern: truncate generic LDS pointer to its 32-bit offset.
    auto gp = reinterpret_cast<const __attribute__((address_space(1))) uint32_t*>(
        reinterpret_cast<uintptr_t>(g));
    auto lp = reinterpret_cast<__attribute__((address_space(3))) uint32_t*>(
        reinterpret_cast<uintptr_t>(l));
    __builtin_amdgcn_global_load_lds(gp, lp, 16, 0, 0);
}

__device__ __forceinline__ f32x4 mfma16(bf16x8 a, bf16x8 b, f32x4 c) {
    return __builtin_amdgcn_mfma_f32_16x16x32_bf16(a, b, c, 0, 0, 0);
}

// ---------------------------------------------------------------------------
// Kernel 1: gate = softmax(logits/10); top-1 expert; per-expert counts.
// ---------------------------------------------------------------------------
__global__ __launch_bounds__(256) void gatek(const float* __restrict__ logits,
                                             int* __restrict__ expert,
                                             float* __restrict__ gatev,
                                             int* __restrict__ cnt) {
    int b = blockIdx.x * 256 + threadIdx.x;
    if (b >= B_ROWS) return;
    const f32x4* lp = (const f32x4*)(logits + (size_t)b * C_EXP);
    float l[16];
#pragma unroll
    for (int i = 0; i < 4; ++i) {
        f32x4 v = lp[i];
        l[i*4+0] = v[0]; l[i*4+1] = v[1]; l[i*4+2] = v[2]; l[i*4+3] = v[3];
    }
    float m = l[0]; int idx = 0;
#pragma unroll
    for (int j = 1; j < 16; ++j)
        if (l[j] > m) { m = l[j]; idx = j; }   // first-max == np.argmax
    float s = 0.f;
#pragma unroll
    for (int j = 0; j < 16; ++j) s += __expf((l[j] - m) * 0.1f);
    expert[b] = idx;
    gatev[b]  = 1.0f / s;          // softmax value at the argmax
    atomicAdd(&cnt[idx], 1);
}

// ---------------------------------------------------------------------------
// Kernel 2: tiny serial scan (16 experts).
// ---------------------------------------------------------------------------
__global__ void scank(const int* __restrict__ cnt, int* __restrict__ offs,
                      int* __restrict__ toff) {
    if (threadIdx.x == 0 && blockIdx.x == 0) {
        int o = 0, to = 0;
        for (int e = 0; e < C_EXP; ++e) {
            offs[e] = o; toff[e] = to;
            o  += cnt[e];
            to += (cnt[e] + 63) >> 6;
        }
        offs[C_EXP] = o; toff[C_EXP] = to;
    }
}

// ---------------------------------------------------------------------------
// Kernel 3: bucket rows by expert.
// ---------------------------------------------------------------------------
__global__ __launch_bounds__(256) void scatk(const int* __restrict__ expert,
                                             const int* __restrict__ offs,
                                             int* __restrict__ cursor,
                                             int* __restrict__ rowlist) {
    int b = blockIdx.x * 256 + threadIdx.x;
    if (b >= B_ROWS) return;
    int e = expert[b];
    int p = atomicAdd(&cursor[e], 1);
    rowlist[offs[e] + p] = b;
}

// ---------------------------------------------------------------------------
// Kernel 4: weights fp32 [C][K][N] -> bf16 transposed [N][K] chunk-major with
// the LDS XOR-swizzle pre-baked (so GEMM stages with linear global_load_lds).
// blocks 0..1151: w1 (K=768,N=384, 12 kc x 6 nb); 1152..2303: w4 (K=384,N=768).
// ---------------------------------------------------------------------------
__global__ __launch_bounds__(256) void wconv(const float* __restrict__ w1,
                                             const float* __restrict__ w4,
                                             char* __restrict__ w1s,
                                             char* __restrict__ w4s) {
    __shared__ float tile[64 * 65];
    int bid = blockIdx.x;
    bool is1 = bid < 1152;
    int lb = is1 ? bid : bid - 1152;
    int c = lb / 72, rem = lb % 72;
    int kc, nb, Nfull;
    const float* src;
    char* chunk;
    if (is1) {
        kc = rem / 6;  nb = rem % 6;  Nfull = H_DIM;
        src   = w1 + (size_t)c * D_DIM * H_DIM;
        chunk = w1s + ((size_t)c * 12 + kc) * 49152;
    } else {
        kc = rem / 12; nb = rem % 12; Nfull = D_DIM;
        src   = w4 + (size_t)c * H_DIM * D_DIM;
        chunk = w4s + ((size_t)c * 6 + kc) * 98304;
    }
    // read 64(k) x 64(n) fp32 tile, coalesced along n
#pragma unroll
    for (int it = 0; it < 4; ++it) {
        int f  = threadIdx.x + it * 256;   // float4 id 0..1023
        int kr = f >> 4, nq = f & 15;
        f32x4 v = *(const f32x4*)(src + (size_t)(kc * 64 + kr) * Nfull + nb * 64 + nq * 4);
        tile[kr * 65 + nq * 4 + 0] = v[0];
        tile[kr * 65 + nq * 4 + 1] = v[1];
        tile[kr * 65 + nq * 4 + 2] = v[2];
        tile[kr * 65 + nq * 4 + 3] = v[3];
    }
    __syncthreads();
    // write transposed+swizzled bf16, 16B stores, coalesced per 128B row
#pragma unroll
    for (int it = 0; it < 2; ++it) {
        int s2 = threadIdx.x + it * 256;   // 0..511
        int nl = s2 >> 3, kg = s2 & 7;
        int n  = nb * 64 + nl;
        bf16x8 p;
#pragma unroll
        for (int j = 0; j < 8; ++j) p[j] = (bf16_t)tile[(kg * 8 + j) * 65 + nl];
        *(bf16x8*)(chunk + n * 128 + ((kg * 16) ^ ((n & 7) << 4))) = p;
    }
}

// ---------------------------------------------------------------------------
// Kernel 5: grouped GEMM + fused epilogue.
// One block = 64 rows of one expert. 512 threads = 8 waves (2M x 2N split).
// LDS (dynamic, 147968 B):
//   [0      , 49152) h     [64][384] bf16, swizzled (row stride 768 B)
//   [49152  , 57344) embA  [64][64]  bf16, swizzled   } stage 1
//   [57344  ,106496) w1chk [384][64] bf16, swizzled   }
//   [49152  ,147456) w4chk [768][64] bf16, swizzled   } stage 2 (alias)
//   [49152  ,147456) ebuf  [64][768] bf16, linear     } epilogue (alias)
//   [147456 ,147712) row indices; [147712,147968) gate values
// ---------------------------------------------------------------------------
#define SMEM_BYTES 147968

__global__ __launch_bounds__(512) void moe_main(
    const float* __restrict__ emb, const float* __restrict__ gatev,
    const int* __restrict__ rowlist, const int* __restrict__ cnt,
    const int* __restrict__ offs, const int* __restrict__ toff,
    const char* __restrict__ w1s, const char* __restrict__ w4s,
    const float* __restrict__ b1, const float* __restrict__ b4,
    float* __restrict__ out) {
    extern __shared__ char smem[];

    int t = blockIdx.x;
    int total = toff[C_EXP];
    if (t >= total) return;
    int e = 0;
#pragma unroll
    for (int i = 1; i < C_EXP; ++i) e = (t >= toff[i]) ? i : e;
    int tin  = t - toff[e];
    int Meff = cnt[e] - tin * 64; if (Meff > 64) Meff = 64;
    int base = offs[e] + tin * 64;

    int*   ridxL = (int*)(smem + 147456);
    float* gateL = (float*)(smem + 147712);
    if (threadIdx.x < 64) {
        int rr = threadIdx.x;
        int p  = base + (rr < Meff ? rr : 0);   // clamp pad rows to a valid row
        int ri = rowlist[p];
        ridxL[rr] = ri;
        gateL[rr] = gatev[ri];
    }

    const int wid  = threadIdx.x >> 6;
    const int lane = threadIdx.x & 63;
    const int l15  = lane & 15, l4 = lane >> 4;
    const int r0   = (wid >> 1) * 16;        // wave's 16-row slice
    const int n10  = (wid & 1) * 192;        // stage1 col slice
    const int n20  = (wid & 1) * 384;        // stage2 col slice

    // ---------------- stage 1: h = relu(emb @ w1 + b1)  [64x384] ----------
    f32x4 acc1[12];
#pragma unroll
    for (int j = 0; j < 12; ++j) acc1[j] = f32x4{0.f, 0.f, 0.f, 0.f};

    for (int kc = 0; kc < 12; ++kc) {
        __syncthreads();
        {   // emb fp32 -> bf16 staging, swizzled ds_write_b128
            int r = threadIdx.x >> 3, seg = threadIdx.x & 7;
            const float* s = emb + (size_t)ridxL[r] * D_DIM + kc * 64 + seg * 8;
            f32x4 f0 = *(const f32x4*)s;
            f32x4 f1 = *(const f32x4*)(s + 4);
            bf16x8 p;
            p[0]=(bf16_t)f0[0]; p[1]=(bf16_t)f0[1]; p[2]=(bf16_t)f0[2]; p[3]=(bf16_t)f0[3];
            p[4]=(bf16_t)f1[0]; p[5]=(bf16_t)f1[1]; p[6]=(bf16_t)f1[2]; p[7]=(bf16_t)f1[3];
            *(bf16x8*)(smem + 49152 + r * 128 + ((seg * 16) ^ ((r & 7) << 4))) = p;
        }
        {   // w1 chunk: 48 KB linear async copy (swizzle pre-baked in global)
            const char* s = w1s + ((size_t)e * 12 + kc) * 49152;
#pragma unroll
            for (int i = 0; i < 6; ++i) {
                int off = i * 8192 + wid * 1024;
                lds_load16(s + off + lane * 16, smem + 57344 + off);
            }
        }
        __syncthreads();
#pragma unroll
        for (int kk = 0; kk < 64; kk += 32) {
            int arow = r0 + l15;
            bf16x8 a = *(const bf16x8*)(smem + 49152 + arow * 128 +
                                        ((kk * 2 + l4 * 16) ^ ((arow & 7) << 4)));
#pragma unroll
            for (int j = 0; j < 12; ++j) {
                int bn = n10 + j * 16 + l15;
                bf16x8 b = *(const bf16x8*)(smem + 57344 + bn * 128 +
                                            ((kk * 2 + l4 * 16) ^ ((bn & 7) << 4)));
                acc1[j] = mfma16(a, b, acc1[j]);
            }
        }
    }
    // h = relu(acc1 + b1) -> bf16 into swizzled LDS (no barrier needed: h
    // region is disjoint from embA/w1chk)
#pragma unroll
    for (int j = 0; j < 12; ++j) {
        int col = n10 + j * 16 + l15;
        float bb = b1[e * H_DIM + col];
#pragma unroll
        for (int v = 0; v < 4; ++v) {
            int row = r0 + l4 * 4 + v;
            float hv = fmaxf(acc1[j][v] + bb, 0.f);
            *(bf16_t*)(smem + row * 768 + ((col * 2) ^ ((row & 7) << 4))) = (bf16_t)hv;
        }
    }
    __syncthreads();

    // ---------------- stage 2: eo = h @ w4  [64x768] ----------------------
    f32x4 acc2[24];
#pragma unroll
    for (int j = 0; j < 24; ++j) acc2[j] = f32x4{0.f, 0.f, 0.f, 0.f};

    for (int kc = 0; kc < 6; ++kc) {
        if (kc) __syncthreads();
        const char* s = w4s + ((size_t)e * 6 + kc) * 98304;
#pragma unroll
        for (int i = 0; i < 12; ++i) {
            int off = i * 8192 + wid * 1024;
            lds_load16(s + off + lane * 16, smem + 49152 + off);
        }
        __syncthreads();
#pragma unroll
        for (int kk = 0; kk < 64; kk += 32) {
            int arow = r0 + l15;
            int kh   = kc * 64 + kk;
            bf16x8 a = *(const bf16x8*)(smem + arow * 768 +
                                        ((kh * 2 + l4 * 16) ^ ((arow & 7) << 4)));
#pragma unroll
            for (int j = 0; j < 24; ++j) {
                int bn = n20 + j * 16 + l15;
                bf16x8 b = *(const bf16x8*)(smem + 49152 + bn * 128 +
                                            ((kk * 2 + l4 * 16) ^ ((bn & 7) << 4)));
                acc2[j] = mfma16(a, b, acc2[j]);
            }
        }
    }
    __syncthreads();   // before ebuf overwrites w4chk

    // park raw expert output in LDS (bf16, linear [64][768])
    bf16_t* ebuf = (bf16_t*)(smem + 49152);
#pragma unroll
    for (int j = 0; j < 24; ++j) {
        int col = n20 + j * 16 + l15;
#pragma unroll
        for (int v = 0; v < 4; ++v) {
            int row = r0 + l4 * 4 + v;
            ebuf[row * 768 + col] = (bf16_t)acc2[j][v];
        }
    }
    __syncthreads();

    // ---------------- epilogue: gate, l2norm, +emb, l2norm, scatter -------
    for (int rr = 0; rr < 8; ++rr) {
        int r = wid * 8 + rr;
        if (r >= Meff) break;               // wave-uniform
        int   ridx = ridxL[r];
        float g    = gateL[r];
        float comb[12];
        float ss = 0.f;
#pragma unroll
        for (int i = 0; i < 3; ++i) {
            int col = i * 256 + lane * 4;
            bf16x4 ev = *(const bf16x4*)(ebuf + r * 768 + col);
            f32x4  bv = *(const f32x4*)(b4 + e * D_DIM + col);
#pragma unroll
            for (int q = 0; q < 4; ++q) {
                float cv = ((float)ev[q] + bv[q]) * g;
                comb[i * 4 + q] = cv;
                ss += cv * cv;
            }
        }
#pragma unroll
        for (int o = 32; o > 0; o >>= 1) ss += __shfl_xor(ss, o, 64);
        float inv1 = 1.0f / fmaxf(sqrtf(ss), 1e-6f);

        float ov[12];
        float ss2 = 0.f;
#pragma unroll
        for (int i = 0; i < 3; ++i) {
            int col = i * 256 + lane * 4;
            f32x4 em = *(const f32x4*)(emb + (size_t)ridx * D_DIM + col);
#pragma unroll
            for (int q = 0; q < 4; ++q) {
                float o2 = comb[i * 4 + q] * inv1 + em[q];
                ov[i * 4 + q] = o2;
                ss2 += o2 * o2;
            }
        }
#pragma unroll
        for (int o = 32; o > 0; o >>= 1) ss2 += __shfl_xor(ss2, o, 64);
        float inv2 = 1.0f / fmaxf(sqrtf(ss2), 1e-12f);
#pragma unroll
        for (int i = 0; i < 3; ++i) {
            int col = i * 256 + lane * 4;
            f32x4 w;
#pragma unroll
            for (int q = 0; q < 4; ++q) w[q] = ov[i * 4 + q] * inv2;
            *(f32x4*)(out + (size_t)ridx * D_DIM + col) = w;
        }
    }
}

// ---------------------------------------------------------------------------
extern "C" void kernel_launch(void* const* d_in, const int* in_sizes, int n_in,
                              void* d_out, int out_size, void* d_ws, size_t ws_size,
                              hipStream_t stream) {
    const float* emb    = (const float*)d_in[0];
    const float* logits = (const float*)d_in[1];
    const float* w1     = (const float*)d_in[2];
    const float* b1     = (const float*)d_in[3];
    const float* w4     = (const float*)d_in[4];
    const float* b4     = (const float*)d_in[5];
    float* out = (float*)d_out;
    char*  ws  = (char*)d_ws;
    if (ws_size < WS_END) return;  // workspace too small -> fail loudly (poisoned out)

    int*   cnt     = (int*)(ws + WS_CNT);
    int*   cur     = (int*)(ws + WS_CUR);
    int*   offs    = (int*)(ws + WS_OFF);
    int*   toff    = (int*)(ws + WS_TOFF);
    int*   expert  = (int*)(ws + WS_EXP);
    float* gatev   = (float*)(ws + WS_GATE);
    int*   rowlist = (int*)(ws + WS_ROW);
    char*  w1s     = ws + WS_W1;
    char*  w4s     = ws + WS_W4;

    hipMemsetAsync(ws, 0, 512, stream);
    gatek<<<dim3(B_ROWS / 256), dim3(256), 0, stream>>>(logits, expert, gatev, cnt);
    scank<<<dim3(1), dim3(64), 0, stream>>>(cnt, offs, toff);
    scatk<<<dim3(B_ROWS / 256), dim3(256), 0, stream>>>(expert, offs, cur, rowlist);
    wconv<<<dim3(2304), dim3(256), 0, stream>>>(w1, w4, w1s, w4s);

    (void)hipFuncSetAttribute((const void*)moe_main,
                              hipFuncAttributeMaxDynamicSharedMemorySize, SMEM_BYTES);
    // max tiles = B/64 + C = 272 (blocks beyond the real tile count exit early)
    moe_main<<<dim3(272), dim3(512), SMEM_BYTES, stream>>>(
        emb, gatev, rowlist, cnt, offs, toff, w1s, w4s, b1, b4, out);
}

// Round 2
// 177.703 us; speedup vs baseline: 1.1826x; 1.1826x over previous
//
#include <hip/hip_runtime.h>
#include <stdint.h>

// ---------------------------------------------------------------------------
// MoEBiEncoder: top-1 MoE (C=16 experts), per-row 768 -> relu(384) -> 768,
// gate-scale, l2norm, +residual, l2norm.  B=16384, D=768, H=384.
//
// v2: B-operands (weights) streamed from global (fragment-major bf16 layout,
//     1 KB per MFMA fragment) -> no weight LDS staging, no inner-loop
//     barriers, compiler-pipelined loads. 32-row tiles, 74 KB LDS,
//     2 blocks/CU, 16 waves/CU.
// ---------------------------------------------------------------------------

#define B_ROWS 16384
#define C_EXP  16
#define D_DIM  768
#define H_DIM  384

typedef __bf16 bf16_t;
typedef __bf16 bf16x8 __attribute__((ext_vector_type(8)));
typedef __bf16 bf16x4 __attribute__((ext_vector_type(4)));
typedef float  f32x4  __attribute__((ext_vector_type(4)));

// ---- workspace layout (bytes) ----
static constexpr size_t WS_CNT  = 0;                       // 16 int
static constexpr size_t WS_CUR  = 64;                      // 16 int
static constexpr size_t WS_OFF  = 128;                     // 17 int
static constexpr size_t WS_TOFF = 256;                     // 17 int
static constexpr size_t WS_EXP  = 512;                     // B int
static constexpr size_t WS_GATE = WS_EXP  + (size_t)B_ROWS * 4;
static constexpr size_t WS_ROW  = WS_GATE + (size_t)B_ROWS * 4;
static constexpr size_t WS_W1   = WS_ROW  + (size_t)B_ROWS * 4;   // 197120
static constexpr size_t W_BYTES = (size_t)C_EXP * D_DIM * H_DIM * 2;  // 9437184
static constexpr size_t WS_W4   = WS_W1 + W_BYTES;
static constexpr size_t WS_END  = WS_W4 + W_BYTES;         // ~18.2 MB

// Fragment-major weight layout (per expert, KF = K/32, NF = N/16):
//   frag(kf,nf) is 1024 contiguous bytes; lane l's 16 bytes at l*16 hold
//   w[k0 + (l>>4)*8 + j][n0 + (l&15)], j=0..7  (k0=kf*32, n0=nf*16)
// -> B-fragment load is one coalesced global_load_dwordx4 per lane.
// w1: KF=24, NF=24.  w4: KF=12, NF=48.

__device__ __forceinline__ f32x4 mfma16(bf16x8 a, bf16x8 b, f32x4 c) {
    return __builtin_amdgcn_mfma_f32_16x16x32_bf16(a, b, c, 0, 0, 0);
}

// ---------------------------------------------------------------------------
// Kernel 1: gate = softmax(logits/10); top-1 expert; per-expert counts.
// ---------------------------------------------------------------------------
__global__ __launch_bounds__(256) void gatek(const float* __restrict__ logits,
                                             int* __restrict__ expert,
                                             float* __restrict__ gatev,
                                             int* __restrict__ cnt) {
    int b = blockIdx.x * 256 + threadIdx.x;
    if (b >= B_ROWS) return;
    const f32x4* lp = (const f32x4*)(logits + (size_t)b * C_EXP);
    float l[16];
#pragma unroll
    for (int i = 0; i < 4; ++i) {
        f32x4 v = lp[i];
        l[i*4+0] = v[0]; l[i*4+1] = v[1]; l[i*4+2] = v[2]; l[i*4+3] = v[3];
    }
    float m = l[0]; int idx = 0;
#pragma unroll
    for (int j = 1; j < 16; ++j)
        if (l[j] > m) { m = l[j]; idx = j; }   // first-max == np.argmax
    float s = 0.f;
#pragma unroll
    for (int j = 0; j < 16; ++j) s += __expf((l[j] - m) * 0.1f);
    expert[b] = idx;
    gatev[b]  = 1.0f / s;          // softmax value at the argmax
    atomicAdd(&cnt[idx], 1);
}

// ---------------------------------------------------------------------------
// Kernel 2: tiny serial scan (16 experts). Tiles are 32 rows now.
// ---------------------------------------------------------------------------
__global__ void scank(const int* __restrict__ cnt, int* __restrict__ offs,
                      int* __restrict__ toff) {
    if (threadIdx.x == 0 && blockIdx.x == 0) {
        int o = 0, to = 0;
        for (int e = 0; e < C_EXP; ++e) {
            offs[e] = o; toff[e] = to;
            o  += cnt[e];
            to += (cnt[e] + 31) >> 5;
        }
        offs[C_EXP] = o; toff[C_EXP] = to;
    }
}

// ---------------------------------------------------------------------------
// Kernel 3: bucket rows by expert.
// ---------------------------------------------------------------------------
__global__ __launch_bounds__(256) void scatk(const int* __restrict__ expert,
                                             const int* __restrict__ offs,
                                             int* __restrict__ cursor,
                                             int* __restrict__ rowlist) {
    int b = blockIdx.x * 256 + threadIdx.x;
    if (b >= B_ROWS) return;
    int e = expert[b];
    int p = atomicAdd(&cursor[e], 1);
    rowlist[offs[e] + p] = b;
}

// ---------------------------------------------------------------------------
// Kernel 4: weights fp32 [C][K][N] -> bf16 fragment-major (see layout above).
// blocks 0..1151: w1 (12 kc x 6 nb); 1152..2303: w4 (6 kc x 12 nb).
// Each block transposes a 64k x 64n tile via LDS and emits 8 fragments.
// ---------------------------------------------------------------------------
__global__ __launch_bounds__(256) void wconv(const float* __restrict__ w1,
                                             const float* __restrict__ w4,
                                             char* __restrict__ w1s,
                                             char* __restrict__ w4s) {
    __shared__ float tile[64 * 65];
    int bid = blockIdx.x;
    bool is1 = bid < 1152;
    int lb = is1 ? bid : bid - 1152;
    int c = lb / 72, rem = lb % 72;
    int kc, nb, Nfull, KF, NF;
    const float* src;
    char* dstbase;
    if (is1) {
        kc = rem / 6;  nb = rem % 6;  Nfull = H_DIM; KF = 24; NF = 24;
        src     = w1 + (size_t)c * D_DIM * H_DIM;
        dstbase = w1s;
    } else {
        kc = rem / 12; nb = rem % 12; Nfull = D_DIM; KF = 12; NF = 48;
        src     = w4 + (size_t)c * H_DIM * D_DIM;
        dstbase = w4s;
    }
    // read 64(k) x 64(n) fp32 tile, coalesced along n
#pragma unroll
    for (int it = 0; it < 4; ++it) {
        int f  = threadIdx.x + it * 256;   // float4 id 0..1023
        int kr = f >> 4, nq = f & 15;
        f32x4 v = *(const f32x4*)(src + (size_t)(kc * 64 + kr) * Nfull + nb * 64 + nq * 4);
        tile[kr * 65 + nq * 4 + 0] = v[0];
        tile[kr * 65 + nq * 4 + 1] = v[1];
        tile[kr * 65 + nq * 4 + 2] = v[2];
        tile[kr * 65 + nq * 4 + 3] = v[3];
    }
    __syncthreads();
    // write 8 fragments (2 kf' x 4 nf'), 16B per lane, perfectly coalesced
#pragma unroll
    for (int it = 0; it < 2; ++it) {
        int s2   = threadIdx.x + it * 256;   // 0..511
        int frag = s2 >> 6, lane = s2 & 63;
        int kfl  = frag >> 2, nfl = frag & 3;
        int col  = lane & 15, kq = lane >> 4;
        bf16x8 p;
#pragma unroll
        for (int j = 0; j < 8; ++j)
            p[j] = (bf16_t)tile[(kfl * 32 + kq * 8 + j) * 65 + nfl * 16 + col];
        int kf = kc * 2 + kfl, nf = nb * 4 + nfl;
        size_t off = (((size_t)c * KF + kf) * NF + nf) * 1024 + lane * 16;
        *(bf16x8*)(dstbase + off) = p;
    }
}

// ---------------------------------------------------------------------------
// Kernel 5: grouped GEMM + fused epilogue.
// One block = 32 rows of one expert. 512 threads = 8 waves, wave w owns
// N-slice [w*48, w*48+48) in stage 1 and [w*96, w*96+96) in stage 2,
// all 32 rows (2 MFMA row-groups).
// LDS (dynamic, 73984 B):
//   [0     , 49152) embA [32][768] bf16, XOR-swizzled (also ebuf linear later)
//   [49152 , 73728) h    [32][384] bf16, XOR-swizzled
//   [73728 , 73856) row indices; [73856, 73984) gate values
// Barriers: 4 total per block. B-fragments streamed from global (L2-hot).
// ---------------------------------------------------------------------------
#define SMEM_BYTES 73984

__global__ __launch_bounds__(512, 4) void moe_main(
    const float* __restrict__ emb, const float* __restrict__ gatev,
    const int* __restrict__ rowlist, const int* __restrict__ cnt,
    const int* __restrict__ offs, const int* __restrict__ toff,
    const char* __restrict__ w1s, const char* __restrict__ w4s,
    const float* __restrict__ b1, const float* __restrict__ b4,
    float* __restrict__ out) {
    extern __shared__ char smem[];

    // XCD-aware bijective swizzle: grid 528 = 8 * 66
    int bid = blockIdx.x;
    int t   = (bid & 7) * 66 + (bid >> 3);

    int total = toff[C_EXP];
    if (t >= total) return;
    int e = 0;
#pragma unroll
    for (int i = 1; i < C_EXP; ++i) e = (t >= toff[i]) ? i : e;
    int tin  = t - toff[e];
    int Meff = cnt[e] - tin * 32; if (Meff > 32) Meff = 32;
    int base = offs[e] + tin * 32;

    int*   ridxL = (int*)(smem + 73728);
    float* gateL = (float*)(smem + 73856);
    if (threadIdx.x < 32) {
        int rr = threadIdx.x;
        int p  = base + (rr < Meff ? rr : 0);   // clamp pad rows to a valid row
        int ri = rowlist[p];
        ridxL[rr] = ri;
        gateL[rr] = gatev[ri];
    }
    __syncthreads();

    // ---- stage embA: fp32 -> bf16, swizzled [32][768] --------------------
#pragma unroll
    for (int it = 0; it < 6; ++it) {
        int q   = threadIdx.x + it * 512;   // 0..3071 chunks of 8 k
        int row = q / 96, kq = q % 96;
        const float* s = emb + (size_t)ridxL[row] * D_DIM + kq * 8;
        f32x4 f0 = *(const f32x4*)s;
        f32x4 f1 = *(const f32x4*)(s + 4);
        bf16x8 p;
        p[0]=(bf16_t)f0[0]; p[1]=(bf16_t)f0[1]; p[2]=(bf16_t)f0[2]; p[3]=(bf16_t)f0[3];
        p[4]=(bf16_t)f1[0]; p[5]=(bf16_t)f1[1]; p[6]=(bf16_t)f1[2]; p[7]=(bf16_t)f1[3];
        *(bf16x8*)(smem + row * 1536 + ((kq * 16) ^ ((row & 7) << 4))) = p;
    }
    __syncthreads();

    const int wid  = threadIdx.x >> 6;
    const int lane = threadIdx.x & 63;
    const int l15  = lane & 15, l4 = lane >> 4;

    // ---------------- stage 1: h = relu(emb @ w1 + b1)  [32x384] ----------
    f32x4 acc1[2][3];
#pragma unroll
    for (int rg = 0; rg < 2; ++rg)
#pragma unroll
        for (int j = 0; j < 3; ++j) acc1[rg][j] = f32x4{0.f, 0.f, 0.f, 0.f};

    const char* w1e = w1s + (size_t)e * 589824;
#pragma unroll
    for (int kf = 0; kf < 24; ++kf) {
        int kb = (kf * 32 + l4 * 8) * 2;
        bf16x8 a0 = *(const bf16x8*)(smem + l15 * 1536 + (kb ^ ((l15 & 7) << 4)));
        bf16x8 a1 = *(const bf16x8*)(smem + (l15 + 16) * 1536 + (kb ^ ((l15 & 7) << 4)));
#pragma unroll
        for (int jn = 0; jn < 3; ++jn) {
            bf16x8 b = *(const bf16x8*)(w1e + ((size_t)(kf * 24 + wid * 3 + jn)) * 1024 + lane * 16);
            acc1[0][jn] = mfma16(a0, b, acc1[0][jn]);
            acc1[1][jn] = mfma16(a1, b, acc1[1][jn]);
        }
    }
    // h = relu(acc1 + b1) -> bf16 swizzled LDS
#pragma unroll
    for (int jn = 0; jn < 3; ++jn) {
        int col = wid * 48 + jn * 16 + l15;
        float bb = b1[e * H_DIM + col];
#pragma unroll
        for (int rg = 0; rg < 2; ++rg)
#pragma unroll
            for (int v = 0; v < 4; ++v) {
                int row = rg * 16 + l4 * 4 + v;
                float hv = fmaxf(acc1[rg][jn][v] + bb, 0.f);
                *(bf16_t*)(smem + 49152 + row * 768 + ((col * 2) ^ ((row & 7) << 4))) = (bf16_t)hv;
            }
    }
    __syncthreads();

    // ---------------- stage 2: eo = h @ w4  [32x768] ----------------------
    f32x4 acc2[2][6];
#pragma unroll
    for (int rg = 0; rg < 2; ++rg)
#pragma unroll
        for (int j = 0; j < 6; ++j) acc2[rg][j] = f32x4{0.f, 0.f, 0.f, 0.f};

    const char* w4e = w4s + (size_t)e * 589824;
#pragma unroll
    for (int kf = 0; kf < 12; ++kf) {
        int kb = (kf * 32 + l4 * 8) * 2;
        bf16x8 a0 = *(const bf16x8*)(smem + 49152 + l15 * 768 + (kb ^ ((l15 & 7) << 4)));
        bf16x8 a1 = *(const bf16x8*)(smem + 49152 + (l15 + 16) * 768 + (kb ^ ((l15 & 7) << 4)));
#pragma unroll
        for (int jn = 0; jn < 6; ++jn) {
            bf16x8 b = *(const bf16x8*)(w4e + ((size_t)(kf * 48 + wid * 6 + jn)) * 1024 + lane * 16);
            acc2[0][jn] = mfma16(a0, b, acc2[0][jn]);
            acc2[1][jn] = mfma16(a1, b, acc2[1][jn]);
        }
    }

    // ebuf = (acc2 + b4) * gate, bf16 linear [32][768] (aliases embA region)
    bf16_t* ebuf = (bf16_t*)smem;
#pragma unroll
    for (int jn = 0; jn < 6; ++jn) {
        int col = wid * 96 + jn * 16 + l15;
        float bb = b4[e * D_DIM + col];
#pragma unroll
        for (int rg = 0; rg < 2; ++rg)
#pragma unroll
            for (int v = 0; v < 4; ++v) {
                int row = rg * 16 + l4 * 4 + v;
                ebuf[row * 768 + col] = (bf16_t)((acc2[rg][jn][v] + bb) * gateL[row]);
            }
    }
    __syncthreads();

    // ---------------- epilogue: l2norm, +emb, l2norm, scatter -------------
    for (int rr = 0; rr < 4; ++rr) {
        int r = wid * 4 + rr;
        if (r >= Meff) break;               // wave-uniform
        int ridx = ridxL[r];
        float comb[12];
        float ss = 0.f;
#pragma unroll
        for (int i = 0; i < 3; ++i) {
            int col = i * 256 + lane * 4;
            bf16x4 ev = *(const bf16x4*)(ebuf + r * 768 + col);
#pragma unroll
            for (int q = 0; q < 4; ++q) {
                float cv = (float)ev[q];
                comb[i * 4 + q] = cv;
                ss += cv * cv;
            }
        }
#pragma unroll
        for (int o = 32; o > 0; o >>= 1) ss += __shfl_xor(ss, o, 64);
        float inv1 = 1.0f / fmaxf(sqrtf(ss), 1e-6f);

        float ov[12];
        float ss2 = 0.f;
#pragma unroll
        for (int i = 0; i < 3; ++i) {
            int col = i * 256 + lane * 4;
            f32x4 em = *(const f32x4*)(emb + (size_t)ridx * D_DIM + col);
#pragma unroll
            for (int q = 0; q < 4; ++q) {
                float o2 = comb[i * 4 + q] * inv1 + em[q];
                ov[i * 4 + q] = o2;
                ss2 += o2 * o2;
            }
        }
#pragma unroll
        for (int o = 32; o > 0; o >>= 1) ss2 += __shfl_xor(ss2, o, 64);
        float inv2 = 1.0f / fmaxf(sqrtf(ss2), 1e-12f);
#pragma unroll
        for (int i = 0; i < 3; ++i) {
            int col = i * 256 + lane * 4;
            f32x4 w;
#pragma unroll
            for (int q = 0; q < 4; ++q) w[q] = ov[i * 4 + q] * inv2;
            *(f32x4*)(out + (size_t)ridx * D_DIM + col) = w;
        }
    }
}

// ---------------------------------------------------------------------------
extern "C" void kernel_launch(void* const* d_in, const int* in_sizes, int n_in,
                              void* d_out, int out_size, void* d_ws, size_t ws_size,
                              hipStream_t stream) {
    const float* emb    = (const float*)d_in[0];
    const float* logits = (const float*)d_in[1];
    const float* w1     = (const float*)d_in[2];
    const float* b1     = (const float*)d_in[3];
    const float* w4     = (const float*)d_in[4];
    const float* b4     = (const float*)d_in[5];
    float* out = (float*)d_out;
    char*  ws  = (char*)d_ws;
    if (ws_size < WS_END) return;  // workspace too small -> fail loudly (poisoned out)

    int*   cnt     = (int*)(ws + WS_CNT);
    int*   cur     = (int*)(ws + WS_CUR);
    int*   offs    = (int*)(ws + WS_OFF);
    int*   toff    = (int*)(ws + WS_TOFF);
    int*   expert  = (int*)(ws + WS_EXP);
    float* gatev   = (float*)(ws + WS_GATE);
    int*   rowlist = (int*)(ws + WS_ROW);
    char*  w1s     = ws + WS_W1;
    char*  w4s     = ws + WS_W4;

    hipMemsetAsync(ws, 0, 512, stream);
    gatek<<<dim3(B_ROWS / 256), dim3(256), 0, stream>>>(logits, expert, gatev, cnt);
    scank<<<dim3(1), dim3(64), 0, stream>>>(cnt, offs, toff);
    scatk<<<dim3(B_ROWS / 256), dim3(256), 0, stream>>>(expert, offs, cur, rowlist);
    wconv<<<dim3(2304), dim3(256), 0, stream>>>(w1, w4, w1s, w4s);

    (void)hipFuncSetAttribute((const void*)moe_main,
                              hipFuncAttributeMaxDynamicSharedMemorySize, SMEM_BYTES);
    // max tiles = sum_e ceil(cnt_e/32) <= 527; grid 528 = 8*66 (swizzle-friendly)
    moe_main<<<dim3(528), dim3(512), SMEM_BYTES, stream>>>(
        emb, gatev, rowlist, cnt, offs, toff, w1s, w4s, b1, b4, out);
}

// Round 3
// 94.424 us; speedup vs baseline: 2.2257x; 1.8820x over previous
//
#include <hip/hip_runtime.h>
#include <stdint.h>

// ---------------------------------------------------------------------------
// MoEBiEncoder: top-1 MoE (C=16 experts), per-row 768 -> relu(384) -> 768,
// gate-scale, l2norm, +residual, l2norm.  B=16384, D=768, H=384.
//
// v3: explicit B-fragment software pipeline (no barriers in K-loops),
//     reduction-based epilogue (no ebuf LDS round trip), hierarchical
//     atomics for gate/scatter, gate merged into the weight-convert dispatch.
// ---------------------------------------------------------------------------

#define B_ROWS 16384
#define C_EXP  16
#define D_DIM  768
#define H_DIM  384

typedef __bf16 bf16_t;
typedef __bf16 bf16x8 __attribute__((ext_vector_type(8)));
typedef float  f32x4  __attribute__((ext_vector_type(4)));

// ---- workspace layout (bytes) ----
static constexpr size_t WS_CNT  = 0;                       // 16 int
static constexpr size_t WS_CUR  = 64;                      // 16 int
static constexpr size_t WS_OFF  = 128;                     // 17 int
static constexpr size_t WS_TOFF = 256;                     // 17 int
static constexpr size_t WS_EXP  = 512;                     // B int
static constexpr size_t WS_GATE = WS_EXP  + (size_t)B_ROWS * 4;
static constexpr size_t WS_ROW  = WS_GATE + (size_t)B_ROWS * 4;
static constexpr size_t WS_W1   = WS_ROW  + (size_t)B_ROWS * 4;
static constexpr size_t W_BYTES = (size_t)C_EXP * D_DIM * H_DIM * 2;  // 9437184
static constexpr size_t WS_W4   = WS_W1 + W_BYTES;
static constexpr size_t WS_END  = WS_W4 + W_BYTES;         // ~18.2 MB

// Fragment-major weight layout (per expert, KF = K/32, NF = N/16):
//   frag(kf,nf) = 1024 contiguous bytes; lane l's 16B at l*16 hold
//   w[k0 + (l>>4)*8 + j][n0 + (l&15)], j=0..7.
// w1: KF=24, NF=24.  w4: KF=12, NF=48.

__device__ __forceinline__ f32x4 mfma16(bf16x8 a, bf16x8 b, f32x4 c) {
    return __builtin_amdgcn_mfma_f32_16x16x32_bf16(a, b, c, 0, 0, 0);
}

// ---------------------------------------------------------------------------
// Kernel 1 "prep": blocks 0..2303 convert weights; blocks 2304..2335 do the
// gate (softmax/argmax) + per-expert counts via LDS histogram.
// ---------------------------------------------------------------------------
__global__ __launch_bounds__(512) void prep(const float* __restrict__ w1,
                                            const float* __restrict__ w4,
                                            const float* __restrict__ logits,
                                            char* __restrict__ w1s,
                                            char* __restrict__ w4s,
                                            int* __restrict__ expert,
                                            float* __restrict__ gatev,
                                            int* __restrict__ cnt) {
    __shared__ float tile[64 * 65];
    __shared__ int   hist[16];
    int bid = blockIdx.x;

    if (bid >= 2304) {
        // ---------------- gate part: 32 blocks x 512 threads --------------
        if (threadIdx.x < 16) hist[threadIdx.x] = 0;
        __syncthreads();
        int b = (bid - 2304) * 512 + threadIdx.x;   // 0..16383
        const f32x4* lp = (const f32x4*)(logits + (size_t)b * C_EXP);
        float l[16];
#pragma unroll
        for (int i = 0; i < 4; ++i) {
            f32x4 v = lp[i];
            l[i*4+0] = v[0]; l[i*4+1] = v[1]; l[i*4+2] = v[2]; l[i*4+3] = v[3];
        }
        float m = l[0]; int idx = 0;
#pragma unroll
        for (int j = 1; j < 16; ++j)
            if (l[j] > m) { m = l[j]; idx = j; }   // first-max == np.argmax
        float s = 0.f;
#pragma unroll
        for (int j = 0; j < 16; ++j) s += __expf((l[j] - m) * 0.1f);
        expert[b] = idx;
        gatev[b]  = 1.0f / s;          // softmax value at the argmax
        atomicAdd(&hist[idx], 1);      // LDS atomic (fast)
        __syncthreads();
        if (threadIdx.x < 16) {
            int c = hist[threadIdx.x];
            if (c) atomicAdd(&cnt[threadIdx.x], c);   // <=16 global atomics/blk
        }
        return;
    }

    // ---------------- weight convert: fp32 [K][N] -> bf16 fragment-major --
    bool is1 = bid < 1152;
    int lb = is1 ? bid : bid - 1152;
    int c = lb / 72, rem = lb % 72;
    int kc, nb, Nfull, KF, NF;
    const float* src;
    char* dstbase;
    if (is1) {
        kc = rem / 6;  nb = rem % 6;  Nfull = H_DIM; KF = 24; NF = 24;
        src     = w1 + (size_t)c * D_DIM * H_DIM;
        dstbase = w1s;
    } else {
        kc = rem / 12; nb = rem % 12; Nfull = D_DIM; KF = 12; NF = 48;
        src     = w4 + (size_t)c * H_DIM * D_DIM;
        dstbase = w4s;
    }
    // read 64(k) x 64(n) fp32 tile, coalesced along n
#pragma unroll
    for (int it = 0; it < 2; ++it) {
        int f  = threadIdx.x + it * 512;   // float4 id 0..1023
        int kr = f >> 4, nq = f & 15;
        f32x4 v = *(const f32x4*)(src + (size_t)(kc * 64 + kr) * Nfull + nb * 64 + nq * 4);
        tile[kr * 65 + nq * 4 + 0] = v[0];
        tile[kr * 65 + nq * 4 + 1] = v[1];
        tile[kr * 65 + nq * 4 + 2] = v[2];
        tile[kr * 65 + nq * 4 + 3] = v[3];
    }
    __syncthreads();
    // write 8 fragments (one per 64-thread group), 16B/lane coalesced
    {
        int frag = threadIdx.x >> 6, lane = threadIdx.x & 63;
        int kfl  = frag >> 2, nfl = frag & 3;
        int col  = lane & 15, kq = lane >> 4;
        bf16x8 p;
#pragma unroll
        for (int j = 0; j < 8; ++j)
            p[j] = (bf16_t)tile[(kfl * 32 + kq * 8 + j) * 65 + nfl * 16 + col];
        int kf = kc * 2 + kfl, nf = nb * 4 + nfl;
        size_t off = (((size_t)c * KF + kf) * NF + nf) * 1024 + lane * 16;
        *(bf16x8*)(dstbase + off) = p;
    }
}

// ---------------------------------------------------------------------------
// Kernel 2: tiny serial scan (16 experts), 32-row tiles.
// ---------------------------------------------------------------------------
__global__ void scank(const int* __restrict__ cnt, int* __restrict__ offs,
                      int* __restrict__ toff) {
    if (threadIdx.x == 0 && blockIdx.x == 0) {
        int o = 0, to = 0;
        for (int e = 0; e < C_EXP; ++e) {
            offs[e] = o; toff[e] = to;
            o  += cnt[e];
            to += (cnt[e] + 31) >> 5;
        }
        offs[C_EXP] = o; toff[C_EXP] = to;
    }
}

// ---------------------------------------------------------------------------
// Kernel 3: bucket rows by expert (hierarchical: LDS rank + 16 atomics/blk).
// ---------------------------------------------------------------------------
__global__ __launch_bounds__(512) void scatk(const int* __restrict__ expert,
                                             const int* __restrict__ offs,
                                             int* __restrict__ cursor,
                                             int* __restrict__ rowlist) {
    __shared__ int lcur[16], lbase[16];
    int b = blockIdx.x * 512 + threadIdx.x;   // grid 32 -> 0..16383
    if (threadIdx.x < 16) lcur[threadIdx.x] = 0;
    __syncthreads();
    int e = expert[b];
    int p = atomicAdd(&lcur[e], 1);           // LDS atomic
    __syncthreads();
    if (threadIdx.x < 16) {
        int c = lcur[threadIdx.x];
        lbase[threadIdx.x] = c ? atomicAdd(&cursor[threadIdx.x], c) : 0;
    }
    __syncthreads();
    rowlist[offs[e] + lbase[e] + p] = b;
}

// ---------------------------------------------------------------------------
// Kernel 4: grouped GEMM + fused epilogue.
// One block = 32 rows of one expert, 512 threads = 8 waves (N-split only).
// K-loops are barrier-free with explicit 1-deep B prefetch.
// LDS (76032 B): embA[32][768]swz @0; h[32][384]swz @49152; ssb1 @73728;
//                ssb2 @74752; ridx @75776; gate @75904.
// ---------------------------------------------------------------------------
#define SMEM_BYTES 76032

__global__ __launch_bounds__(512, 4) void moe_main(
    const float* __restrict__ emb, const float* __restrict__ gatev,
    const int* __restrict__ rowlist, const int* __restrict__ cnt,
    const int* __restrict__ offs, const int* __restrict__ toff,
    const char* __restrict__ w1s, const char* __restrict__ w4s,
    const float* __restrict__ b1, const float* __restrict__ b4,
    float* __restrict__ out) {
    extern __shared__ char smem[];

    // XCD-aware bijective swizzle: grid 528 = 8 * 66
    int bid = blockIdx.x;
    int t   = (bid & 7) * 66 + (bid >> 3);

    int total = toff[C_EXP];
    if (t >= total) return;
    int e = 0;
#pragma unroll
    for (int i = 1; i < C_EXP; ++i) e = (t >= toff[i]) ? i : e;
    int tin  = t - toff[e];
    int Meff = cnt[e] - tin * 32; if (Meff > 32) Meff = 32;
    int base = offs[e] + tin * 32;

    int*   ridxL = (int*)(smem + 75776);
    float* gateL = (float*)(smem + 75904);
    float* ssb1  = (float*)(smem + 73728);   // [32][8]
    float* ssb2  = (float*)(smem + 74752);   // [32][8]
    if (threadIdx.x < 32) {
        int rr = threadIdx.x;
        int p  = base + (rr < Meff ? rr : 0);   // clamp pad rows
        int ri = rowlist[p];
        ridxL[rr] = ri;
        gateL[rr] = gatev[ri];
    }

    const int wid  = threadIdx.x >> 6;
    const int lane = threadIdx.x & 63;
    const int l15  = lane & 15, l4 = lane >> 4;

    const char* w1e = w1s + (size_t)e * 589824;
    const char* w4e = w4s + (size_t)e * 589824;

    // issue first stage-1 B fragments before staging (overlap with conversion)
    auto ldB1 = [&](int kf, int jn) {
        return *(const bf16x8*)(w1e + ((size_t)(kf * 24 + wid * 3 + jn)) * 1024 + lane * 16);
    };
    auto ldB4 = [&](int kf, int jn) {
        return *(const bf16x8*)(w4e + ((size_t)(kf * 48 + wid * 6 + jn)) * 1024 + lane * 16);
    };
    bf16x8 cb0 = ldB1(0, 0), cb1 = ldB1(0, 1), cb2 = ldB1(0, 2);

    __syncthreads();   // (1) ridxL visible

    // ---- stage embA: fp32 -> bf16, swizzled [32][768] --------------------
#pragma unroll
    for (int it = 0; it < 6; ++it) {
        int q   = threadIdx.x + it * 512;   // 0..3071 chunks of 8 k
        int row = q / 96, kq = q % 96;
        const float* s = emb + (size_t)ridxL[row] * D_DIM + kq * 8;
        f32x4 f0 = *(const f32x4*)s;
        f32x4 f1 = *(const f32x4*)(s + 4);
        bf16x8 p;
        p[0]=(bf16_t)f0[0]; p[1]=(bf16_t)f0[1]; p[2]=(bf16_t)f0[2]; p[3]=(bf16_t)f0[3];
        p[4]=(bf16_t)f1[0]; p[5]=(bf16_t)f1[1]; p[6]=(bf16_t)f1[2]; p[7]=(bf16_t)f1[3];
        *(bf16x8*)(smem + row * 1536 + ((kq * 16) ^ ((row & 7) << 4))) = p;
    }
    __syncthreads();   // (2) embA visible

    // ---------------- stage 1: h = relu(emb @ w1 + b1)  [32x384] ----------
    f32x4 acc1[2][3];
#pragma unroll
    for (int rg = 0; rg < 2; ++rg)
#pragma unroll
        for (int j = 0; j < 3; ++j) acc1[rg][j] = f32x4{0.f, 0.f, 0.f, 0.f};

#pragma unroll
    for (int kf = 0; kf < 24; ++kf) {
        bf16x8 nb0, nb1, nb2;
        if (kf + 1 < 24) { nb0 = ldB1(kf+1, 0); nb1 = ldB1(kf+1, 1); nb2 = ldB1(kf+1, 2); }
        int kb = (kf * 32 + l4 * 8) * 2;
        bf16x8 a0 = *(const bf16x8*)(smem + l15 * 1536 + (kb ^ ((l15 & 7) << 4)));
        bf16x8 a1 = *(const bf16x8*)(smem + (l15 + 16) * 1536 + (kb ^ ((l15 & 7) << 4)));
        acc1[0][0] = mfma16(a0, cb0, acc1[0][0]);
        acc1[1][0] = mfma16(a1, cb0, acc1[1][0]);
        acc1[0][1] = mfma16(a0, cb1, acc1[0][1]);
        acc1[1][1] = mfma16(a1, cb1, acc1[1][1]);
        acc1[0][2] = mfma16(a0, cb2, acc1[0][2]);
        acc1[1][2] = mfma16(a1, cb2, acc1[1][2]);
        if (kf + 1 < 24) { cb0 = nb0; cb1 = nb1; cb2 = nb2; }
    }

    // issue first stage-2 B fragments before the h barrier
    bf16x8 db0 = ldB4(0, 0), db1 = ldB4(0, 1), db2 = ldB4(0, 2);
    bf16x8 db3 = ldB4(0, 3), db4 = ldB4(0, 4), db5 = ldB4(0, 5);

    // h = relu(acc1 + b1) -> bf16 swizzled LDS
#pragma unroll
    for (int jn = 0; jn < 3; ++jn) {
        int col = wid * 48 + jn * 16 + l15;
        float bb = b1[e * H_DIM + col];
#pragma unroll
        for (int rg = 0; rg < 2; ++rg)
#pragma unroll
            for (int v = 0; v < 4; ++v) {
                int row = rg * 16 + l4 * 4 + v;
                float hv = fmaxf(acc1[rg][jn][v] + bb, 0.f);
                *(bf16_t*)(smem + 49152 + row * 768 + ((col * 2) ^ ((row & 7) << 4))) = (bf16_t)hv;
            }
    }
    __syncthreads();   // (3) h visible

    // ---------------- stage 2: eo = h @ w4  [32x768] ----------------------
    f32x4 acc2[2][6];
#pragma unroll
    for (int rg = 0; rg < 2; ++rg)
#pragma unroll
        for (int j = 0; j < 6; ++j) acc2[rg][j] = f32x4{0.f, 0.f, 0.f, 0.f};

#pragma unroll
    for (int kf = 0; kf < 12; ++kf) {
        bf16x8 nb0, nb1, nb2, nb3, nb4, nb5;
        if (kf + 1 < 12) {
            nb0 = ldB4(kf+1, 0); nb1 = ldB4(kf+1, 1); nb2 = ldB4(kf+1, 2);
            nb3 = ldB4(kf+1, 3); nb4 = ldB4(kf+1, 4); nb5 = ldB4(kf+1, 5);
        }
        int kb = (kf * 32 + l4 * 8) * 2;
        bf16x8 a0 = *(const bf16x8*)(smem + 49152 + l15 * 768 + (kb ^ ((l15 & 7) << 4)));
        bf16x8 a1 = *(const bf16x8*)(smem + 49152 + (l15 + 16) * 768 + (kb ^ ((l15 & 7) << 4)));
        acc2[0][0] = mfma16(a0, db0, acc2[0][0]);
        acc2[1][0] = mfma16(a1, db0, acc2[1][0]);
        acc2[0][1] = mfma16(a0, db1, acc2[0][1]);
        acc2[1][1] = mfma16(a1, db1, acc2[1][1]);
        acc2[0][2] = mfma16(a0, db2, acc2[0][2]);
        acc2[1][2] = mfma16(a1, db2, acc2[1][2]);
        acc2[0][3] = mfma16(a0, db3, acc2[0][3]);
        acc2[1][3] = mfma16(a1, db3, acc2[1][3]);
        acc2[0][4] = mfma16(a0, db4, acc2[0][4]);
        acc2[1][4] = mfma16(a1, db4, acc2[1][4]);
        acc2[0][5] = mfma16(a0, db5, acc2[0][5]);
        acc2[1][5] = mfma16(a1, db5, acc2[1][5]);
        if (kf + 1 < 12) { db0 = nb0; db1 = nb1; db2 = nb2; db3 = nb3; db4 = nb4; db5 = nb5; }
    }

    // ---------------- epilogue: gate, l2norm, +emb, l2norm, scatter -------
    // comb = (acc2 + b4) * gate, kept fp32 in regs; cross-wave norm via LDS
    const int colb = wid * 96;
    float part[2][4];
#pragma unroll
    for (int rg = 0; rg < 2; ++rg)
#pragma unroll
        for (int v = 0; v < 4; ++v) part[rg][v] = 0.f;

#pragma unroll
    for (int jn = 0; jn < 6; ++jn) {
        float bb = b4[e * D_DIM + colb + jn * 16 + l15];
#pragma unroll
        for (int rg = 0; rg < 2; ++rg)
#pragma unroll
            for (int v = 0; v < 4; ++v) {
                float cv = (acc2[rg][jn][v] + bb) * gateL[rg * 16 + l4 * 4 + v];
                acc2[rg][jn][v] = cv;
                part[rg][v] += cv * cv;
            }
    }
#pragma unroll
    for (int o = 1; o < 16; o <<= 1)
#pragma unroll
        for (int rg = 0; rg < 2; ++rg)
#pragma unroll
            for (int v = 0; v < 4; ++v) part[rg][v] += __shfl_xor(part[rg][v], o, 64);
    if (l15 == 0)
#pragma unroll
        for (int rg = 0; rg < 2; ++rg)
#pragma unroll
            for (int v = 0; v < 4; ++v) ssb1[(rg * 16 + l4 * 4 + v) * 8 + wid] = part[rg][v];
    __syncthreads();   // (4) ssb1 ready

    int   rloc[2][4];
    size_t rbase[2][4];
    float inv1[2][4];
#pragma unroll
    for (int rg = 0; rg < 2; ++rg)
#pragma unroll
        for (int v = 0; v < 4; ++v) {
            int row = rg * 16 + l4 * 4 + v;
            rloc[rg][v]  = row;
            rbase[rg][v] = (size_t)ridxL[row] * D_DIM;
            float s = 0.f;
#pragma unroll
            for (int w = 0; w < 8; ++w) s += ssb1[row * 8 + w];
            inv1[rg][v] = 1.0f / fmaxf(sqrtf(s), 1e-6f);
        }

    float part2[2][4];
#pragma unroll
    for (int rg = 0; rg < 2; ++rg)
#pragma unroll
        for (int v = 0; v < 4; ++v) part2[rg][v] = 0.f;

#pragma unroll
    for (int jn = 0; jn < 6; ++jn) {
        int col = colb + jn * 16 + l15;
#pragma unroll
        for (int rg = 0; rg < 2; ++rg)
#pragma unroll
            for (int v = 0; v < 4; ++v) {
                float em = emb[rbase[rg][v] + col];
                float o2 = acc2[rg][jn][v] * inv1[rg][v] + em;
                acc2[rg][jn][v] = o2;
                part2[rg][v] += o2 * o2;
            }
    }
#pragma unroll
    for (int o = 1; o < 16; o <<= 1)
#pragma unroll
        for (int rg = 0; rg < 2; ++rg)
#pragma unroll
            for (int v = 0; v < 4; ++v) part2[rg][v] += __shfl_xor(part2[rg][v], o, 64);
    if (l15 == 0)
#pragma unroll
        for (int rg = 0; rg < 2; ++rg)
#pragma unroll
            for (int v = 0; v < 4; ++v) ssb2[rloc[rg][v] * 8 + wid] = part2[rg][v];
    __syncthreads();   // (5) ssb2 ready

#pragma unroll
    for (int rg = 0; rg < 2; ++rg)
#pragma unroll
        for (int v = 0; v < 4; ++v) {
            float s = 0.f;
#pragma unroll
            for (int w = 0; w < 8; ++w) s += ssb2[rloc[rg][v] * 8 + w];
            float inv2 = 1.0f / fmaxf(sqrtf(s), 1e-12f);
            if (rloc[rg][v] < Meff) {
#pragma unroll
                for (int jn = 0; jn < 6; ++jn)
                    out[rbase[rg][v] + colb + jn * 16 + l15] = acc2[rg][jn][v] * inv2;
            }
        }
}

// ---------------------------------------------------------------------------
extern "C" void kernel_launch(void* const* d_in, const int* in_sizes, int n_in,
                              void* d_out, int out_size, void* d_ws, size_t ws_size,
                              hipStream_t stream) {
    const float* emb    = (const float*)d_in[0];
    const float* logits = (const float*)d_in[1];
    const float* w1     = (const float*)d_in[2];
    const float* b1     = (const float*)d_in[3];
    const float* w4     = (const float*)d_in[4];
    const float* b4     = (const float*)d_in[5];
    float* out = (float*)d_out;
    char*  ws  = (char*)d_ws;
    if (ws_size < WS_END) return;  // workspace too small -> fail loudly

    int*   cnt     = (int*)(ws + WS_CNT);
    int*   cur     = (int*)(ws + WS_CUR);
    int*   offs    = (int*)(ws + WS_OFF);
    int*   toff    = (int*)(ws + WS_TOFF);
    int*   expert  = (int*)(ws + WS_EXP);
    float* gatev   = (float*)(ws + WS_GATE);
    int*   rowlist = (int*)(ws + WS_ROW);
    char*  w1s     = ws + WS_W1;
    char*  w4s     = ws + WS_W4;

    hipMemsetAsync(ws, 0, 512, stream);
    // weights convert (2304 blocks) + gate (32 blocks) in one dispatch
    prep<<<dim3(2336), dim3(512), 0, stream>>>(w1, w4, logits, w1s, w4s,
                                               expert, gatev, cnt);
    scank<<<dim3(1), dim3(64), 0, stream>>>(cnt, offs, toff);
    scatk<<<dim3(32), dim3(512), 0, stream>>>(expert, offs, cur, rowlist);

    (void)hipFuncSetAttribute((const void*)moe_main,
                              hipFuncAttributeMaxDynamicSharedMemorySize, SMEM_BYTES);
    // max tiles = sum_e ceil(cnt_e/32) <= 527; grid 528 = 8*66 (swizzle)
    moe_main<<<dim3(528), dim3(512), SMEM_BYTES, stream>>>(
        emb, gatev, rowlist, cnt, offs, toff, w1s, w4s, b1, b4, out);
}